// Round 11
// baseline (2202.183 us; speedup 1.0000x reference)
//
#include <hip/hip_runtime.h>

#define NN 100000
#define NE 1600000
#define DIM 64
#define NPB 128            // nodes per bin
#define NBIN 782           // ceil(NN / NPB)
#define NBINP 1024         // padded for scans
#define ECHUNK 2048        // edges per chunk
#define NCHUNKP 1024       // padded chunk count (real = 782)
#define SBK 128            // src buckets (src>>10 -> 0..97)

__device__ inline ushort f2bf(float f) {            // round-to-nearest-even
    unsigned u = __float_as_uint(f);
    unsigned r = u + 0x7FFFu + ((u >> 16) & 1u);
    return (ushort)(r >> 16);
}
__device__ inline float bf2f(ushort h) {
    return __uint_as_float(((unsigned)h) << 16);
}

// Per-chunk histogram over bins (LDS atomics only). gcounts layout: [bin][chunk].
__global__ __launch_bounds__(256) void k_hist(const int* __restrict__ dst,
                                              int* __restrict__ gcounts) {
    __shared__ int hist[NBINP];
    int tid = threadIdx.x, chunk = blockIdx.x;
    for (int j = tid; j < NBINP; j += 256) hist[j] = 0;
    __syncthreads();
    int base = chunk * ECHUNK;
    int lim = min(base + ECHUNK, NE);
    for (int i = base + tid; i < lim; i += 256)
        atomicAdd(&hist[dst[i] >> 7], 1);
    __syncthreads();
    for (int j = tid; j < NBINP; j += 256)
        gcounts[j * NCHUNKP + chunk] = hist[j];
}

// Per-bin exclusive scan over the chunk axis (row-contiguous, in place).
__global__ __launch_bounds__(256) void k_colscan(int* __restrict__ gcounts,
                                                 int* __restrict__ bintot) {
    __shared__ int sd[256];
    int t = threadIdx.x;
    int* p = gcounts + blockIdx.x * NCHUNKP;
    int v[4], s = 0;
    #pragma unroll
    for (int i = 0; i < 4; i++) { v[i] = p[t * 4 + i]; s += v[i]; }
    sd[t] = s;
    __syncthreads();
    for (int off = 1; off < 256; off <<= 1) {
        int x = (t >= off) ? sd[t - off] : 0;
        __syncthreads();
        sd[t] += x;
        __syncthreads();
    }
    int excl = sd[t] - s;
    #pragma unroll
    for (int i = 0; i < 4; i++) { p[t * 4 + i] = excl; excl += v[i]; }
    if (t == 255) bintot[blockIdx.x] = sd[255];
}

// Exclusive scan of 1024 bin totals -> binbase (+ total at [NBINP]).
__global__ __launch_bounds__(256) void k_binscan(const int* __restrict__ bintot,
                                                 int* __restrict__ binbase) {
    __shared__ int sd[256];
    int t = threadIdx.x;
    int v[4], s = 0;
    #pragma unroll
    for (int i = 0; i < 4; i++) { v[i] = bintot[t * 4 + i]; s += v[i]; }
    sd[t] = s;
    __syncthreads();
    for (int off = 1; off < 256; off <<= 1) {
        int x = (t >= off) ? sd[t - off] : 0;
        __syncthreads();
        sd[t] += x;
        __syncthreads();
    }
    int excl = sd[t] - s;
    #pragma unroll
    for (int i = 0; i < 4; i++) { binbase[t * 4 + i] = excl; excl += v[i]; }
    if (t == 255) binbase[NBINP] = sd[255];
}

// Stable scatter of edges into their bin's contiguous range. No global atomics.
// meta = src (17b) | dst_local (7b) << 17
__global__ __launch_bounds__(256) void k_scatbin(const int* __restrict__ src,
                                                 const int* __restrict__ dst,
                                                 const float* __restrict__ w,
                                                 const int* __restrict__ gcounts,
                                                 const int* __restrict__ binbase,
                                                 int2* __restrict__ binned) {
    __shared__ int lcur[NBINP];
    int tid = threadIdx.x, chunk = blockIdx.x;
    for (int j = tid; j < NBINP; j += 256) lcur[j] = 0;
    __syncthreads();
    int base = chunk * ECHUNK;
    int lim = min(base + ECHUNK, NE);
    for (int i = base + tid; i < lim; i += 256) {
        int d = dst[i];
        int b = d >> 7;
        int r = atomicAdd(&lcur[b], 1);                       // LDS atomic
        int pos = binbase[b] + gcounts[b * NCHUNKP + chunk] + r;
        int meta = src[i] | ((d & 127) << 17);
        binned[pos] = make_int2(meta, __float_as_int(w[i]));
    }
}

// Per-bin: dinv (degree-weight sums) + bucket-sort edges by src>>10 (ascending
// src order for the push-layer's L2-friendly sweep). meta kept intact.
__global__ __launch_bounds__(256) void k_group2(const int2* __restrict__ binned,
                                                const int* __restrict__ binbase,
                                                int2* __restrict__ edata,
                                                float* __restrict__ dinv) {
    __shared__ float nws[NPB];
    __shared__ int bcnt[SBK];
    __shared__ int bcur[SBK];
    __shared__ int sd[SBK];
    int t = threadIdx.x, bin = blockIdx.x;
    int beg = binbase[bin], end = binbase[bin + 1];
    if (t < NPB) nws[t] = 0.f;
    if (t < SBK) bcnt[t] = 0;
    __syncthreads();
    for (int e = beg + t; e < end; e += 256) {
        int2 v = binned[e];
        int dl = ((unsigned)v.x) >> 17;
        int sb = (v.x & 0x1FFFF) >> 10;
        atomicAdd(&nws[dl], __int_as_float(v.y));
        atomicAdd(&bcnt[sb], 1);
    }
    __syncthreads();
    if (t < NPB) {
        int node = bin * NPB + t;
        if (node < NN) dinv[node] = rsqrtf(1.0f + nws[t]);
    }
    int own = (t < SBK) ? bcnt[t] : 0;
    if (t < SBK) sd[t] = own;
    __syncthreads();
    for (int off = 1; off < SBK; off <<= 1) {
        int x = (t >= off && t < SBK) ? sd[t - off] : 0;
        __syncthreads();
        if (t < SBK) sd[t] += x;
        __syncthreads();
    }
    if (t < SBK) bcur[t] = sd[t] - own;
    __syncthreads();
    for (int e = beg + t; e < end; e += 256) {
        int2 v = binned[e];
        int sb = (v.x & 0x1FFFF) >> 10;
        int r = atomicAdd(&bcur[sb], 1);
        edata[beg + r] = v;            // meta (src|dl<<17) preserved
    }
}

// Bake dinv[src]*w into edata.y (edge-parallel, once). dst factor in layer.
__global__ __launch_bounds__(256) void k_norm(int2* __restrict__ edata,
                                              const float* __restrict__ dinv, int e) {
    int i = blockIdx.x * 256 + threadIdx.x;
    if (i < e) {
        int2 v = edata[i];
        edata[i].y = __float_as_int(__int_as_float(v.y) * dinv[v.x & 0x1FFFF]);
    }
}

// Convert fp32 activations/input to bf16 gather table (vectorized x4).
__global__ __launch_bounds__(256) void k_cvt(const float* __restrict__ in,
                                             ushort* __restrict__ outb, int total4) {
    int i = blockIdx.x * 256 + threadIdx.x;
    if (i < total4) {
        float4 v = reinterpret_cast<const float4*>(in)[i];
        ushort4 o;
        o.x = f2bf(v.x); o.y = f2bf(v.y); o.z = f2bf(v.z); o.w = f2bf(v.w);
        reinterpret_cast<ushort4*>(outb)[i] = o;
    }
}

// PUSH-mode fused layer. One block per bin; LDS accumulator acc[128][68].
// Edges streamed in ascending-src order (all blocks sweep the table together).
// Group = 16 lanes (4B channels x4 per lane); 4 edges per group-iteration.
template <int RELU>
__global__ __launch_bounds__(256) void k_layer(const int* __restrict__ binbase,
                                               const int2* __restrict__ edata,
                                               const ushort* __restrict__ Hb,
                                               const float* __restrict__ W,
                                               const float* __restrict__ bias,
                                               const float* __restrict__ dinv,
                                               ushort* __restrict__ OutB,
                                               float* __restrict__ OutF) {
    __shared__ float Wlds[64][64];       // 16 KB
    __shared__ float acc[NPB][68];       // 34.8 KB (pad 68 to spread banks)
    int tid = threadIdx.x;
    #pragma unroll
    for (int t = tid; t < 4096; t += 256) Wlds[t >> 6][t & 63] = W[t];
    #pragma unroll
    for (int t = tid; t < NPB * 17; t += 256)
        *reinterpret_cast<float4*>(&acc[t / 17][(t % 17) * 4]) =
            make_float4(0.f, 0.f, 0.f, 0.f);
    __syncthreads();

    int bin = blockIdx.x;
    int beg = binbase[bin], end = binbase[bin + 1];
    int q = tid >> 4;        // group 0..15
    int j = tid & 15;        // lane in group; channels 4j..4j+3

    for (int b = beg + (q << 2); b < end; b += 64) {
        int i1 = min(b + 1, end - 1), i2 = min(b + 2, end - 1), i3 = min(b + 3, end - 1);
        int2 ev0 = edata[b], ev1 = edata[i1], ev2 = edata[i2], ev3 = edata[i3];
        const ushort4 h0 = *reinterpret_cast<const ushort4*>(
            Hb + ((size_t)(ev0.x & 0x1FFFF) << 6) + (j << 2));
        const ushort4 h1 = *reinterpret_cast<const ushort4*>(
            Hb + ((size_t)(ev1.x & 0x1FFFF) << 6) + (j << 2));
        const ushort4 h2 = *reinterpret_cast<const ushort4*>(
            Hb + ((size_t)(ev2.x & 0x1FFFF) << 6) + (j << 2));
        const ushort4 h3 = *reinterpret_cast<const ushort4*>(
            Hb + ((size_t)(ev3.x & 0x1FFFF) << 6) + (j << 2));
        float n0 = __int_as_float(ev0.y);
        float n1 = (b + 1 < end) ? __int_as_float(ev1.y) : 0.f;
        float n2 = (b + 2 < end) ? __int_as_float(ev2.y) : 0.f;
        float n3 = (b + 3 < end) ? __int_as_float(ev3.y) : 0.f;
        float* a0 = &acc[((unsigned)ev0.x) >> 17][j << 2];
        float* a1 = &acc[((unsigned)ev1.x) >> 17][j << 2];
        float* a2 = &acc[((unsigned)ev2.x) >> 17][j << 2];
        float* a3 = &acc[((unsigned)ev3.x) >> 17][j << 2];
        atomicAdd(a0 + 0, n0 * bf2f(h0.x)); atomicAdd(a0 + 1, n0 * bf2f(h0.y));
        atomicAdd(a0 + 2, n0 * bf2f(h0.z)); atomicAdd(a0 + 3, n0 * bf2f(h0.w));
        atomicAdd(a1 + 0, n1 * bf2f(h1.x)); atomicAdd(a1 + 1, n1 * bf2f(h1.y));
        atomicAdd(a1 + 2, n1 * bf2f(h1.z)); atomicAdd(a1 + 3, n1 * bf2f(h1.w));
        atomicAdd(a2 + 0, n2 * bf2f(h2.x)); atomicAdd(a2 + 1, n2 * bf2f(h2.y));
        atomicAdd(a2 + 2, n2 * bf2f(h2.z)); atomicAdd(a2 + 3, n2 * bf2f(h2.w));
        atomicAdd(a3 + 0, n3 * bf2f(h3.x)); atomicAdd(a3 + 1, n3 * bf2f(h3.y));
        atomicAdd(a3 + 2, n3 * bf2f(h3.z)); atomicAdd(a3 + 3, n3 * bf2f(h3.w));
    }
    __syncthreads();

    // epilogue: node-pairs per wave; in-place self-loop + GEMV from LDS
    int lane = tid & 63, wv = tid >> 6;
    float bl = bias[lane];
    int nbase = bin * NPB + wv * 32;
    #pragma unroll 1
    for (int jj = 0; jj < 32; jj += 2) {
        int na = nbase + jj, nb = na + 1;
        int ja = wv * 32 + jj, jb = ja + 1;
        bool va = na < NN, vb = nb < NN;
        float dna = va ? dinv[na] : 0.f;
        float dnb = vb ? dinv[nb] : 0.f;
        ushort ha = Hb[((size_t)(va ? na : 0) << 6) + lane];
        ushort hb = Hb[((size_t)(vb ? nb : 0) << 6) + lane];
        float ra = fmaf(dna, bf2f(ha), acc[ja][lane]) * dna;
        float rb = fmaf(dnb, bf2f(hb), acc[jb][lane]) * dnb;
        acc[ja][lane] = ra;
        acc[jb][lane] = rb;
        __builtin_amdgcn_wave_barrier();
        float oa = 0.f, ob = 0.f;
        #pragma unroll
        for (int k4 = 0; k4 < 64; k4 += 4) {
            float4 a4 = *reinterpret_cast<const float4*>(&acc[ja][k4]);
            float4 b4 = *reinterpret_cast<const float4*>(&acc[jb][k4]);
            oa = fmaf(a4.x, Wlds[k4 + 0][lane], oa); ob = fmaf(b4.x, Wlds[k4 + 0][lane], ob);
            oa = fmaf(a4.y, Wlds[k4 + 1][lane], oa); ob = fmaf(b4.y, Wlds[k4 + 1][lane], ob);
            oa = fmaf(a4.z, Wlds[k4 + 2][lane], oa); ob = fmaf(b4.z, Wlds[k4 + 2][lane], ob);
            oa = fmaf(a4.w, Wlds[k4 + 3][lane], oa); ob = fmaf(b4.w, Wlds[k4 + 3][lane], ob);
        }
        oa += bl; ob += bl;
        if (RELU) {
            oa = fmaxf(oa, 0.f); ob = fmaxf(ob, 0.f);
            if (va) OutB[((size_t)na << 6) + lane] = f2bf(oa);
            if (vb) OutB[((size_t)nb << 6) + lane] = f2bf(ob);
        } else {
            if (va) OutF[((size_t)na << 6) + lane] = oa;
            if (vb) OutF[((size_t)nb << 6) + lane] = ob;
        }
        __builtin_amdgcn_wave_barrier();
    }
}

extern "C" void kernel_launch(void* const* d_in, const int* in_sizes, int n_in,
                              void* d_out, int out_size, void* d_ws, size_t ws_size,
                              hipStream_t stream) {
    const float* x  = (const float*)d_in[0];
    const int* ei   = (const int*)d_in[1];   // [2][NE] int32
    const float* ew = (const float*)d_in[2];
    const float* W1 = (const float*)d_in[3];
    const float* b1 = (const float*)d_in[4];
    const float* W2 = (const float*)d_in[5];
    const float* b2 = (const float*)d_in[6];
    const float* W3 = (const float*)d_in[7];
    const float* b3 = (const float*)d_in[8];
    float* out = (float*)d_out;

    const int* src = ei;
    const int* dst = ei + NE;

    auto align = [](size_t v) { return (v + 255) / 256 * 256; };
    char* ws = (char*)d_ws;
    // persistent through layers:
    float* dinv    = (float*)ws; ws += align((size_t)NN * 4);
    int*   binbase = (int*)ws;   ws += align(((size_t)NBINP + 1) * 4);
    int2*  edata   = (int2*)ws;  ws += align((size_t)NE * 8);              // 12.8 MB
    // build temporaries, later overlaid by Hb0 (all dead after k_group2):
    char* temp = ws;
    int*  gcounts = (int*)temp;                 // 4 MB
    int*  bintot  = (int*)(temp + align((size_t)NBINP * NCHUNKP * 4));
    int2* binned  = (int2*)((char*)bintot + align((size_t)NBINP * 4));     // 12.8 MB
    ws += align((size_t)NBINP * NCHUNKP * 4) + align((size_t)NBINP * 4)
        + align((size_t)NE * 8);
    ushort* Hb0 = (ushort*)temp;                // 12.8 MB, overlays dead build temps
    // bf16 activations:
    ushort* A1b = (ushort*)ws; ws += align((size_t)NN * DIM * 2);          // 12.8 MB
    ushort* A2b = (ushort*)ws;                                             // 12.8 MB

    const int gE = (NE + 255) / 256;
    const int gC = (NN * DIM / 4 + 255) / 256;

    // ---- deterministic CSR build + per-bin src-sort: zero global atomics ----
    k_hist<<<NCHUNKP, 256, 0, stream>>>(dst, gcounts);
    k_colscan<<<NBINP, 256, 0, stream>>>(gcounts, bintot);
    k_binscan<<<1, 256, 0, stream>>>(bintot, binbase);
    k_scatbin<<<NCHUNKP, 256, 0, stream>>>(src, dst, ew, gcounts, binbase, binned);
    k_group2<<<NBIN, 256, 0, stream>>>(binned, binbase, edata, dinv);
    k_norm<<<gE, 256, 0, stream>>>(edata, dinv, NE);
    k_cvt<<<gC, 256, 0, stream>>>(x, Hb0, NN * DIM / 4);   // after k_group2 (overlay)

    // ---- push-mode fused layers: bf16 gather tables, fp32 math ----
    k_layer<1><<<NBIN, 256, 0, stream>>>(binbase, edata, Hb0, W1, b1, dinv, A1b, nullptr);
    k_layer<1><<<NBIN, 256, 0, stream>>>(binbase, edata, A1b, W2, b2, dinv, A2b, nullptr);
    k_layer<0><<<NBIN, 256, 0, stream>>>(binbase, edata, A2b, W3, b3, dinv, nullptr, out);
}

// Round 12
// 286.482 us; speedup vs baseline: 7.6870x; 7.6870x over previous
//
#include <hip/hip_runtime.h>

#define NN 100000
#define NE 1600000
#define DIM 64
#define NPB 128            // nodes per bin
#define NBIN 782           // ceil(NN / NPB)
#define NBINP 1024         // padded for scans
#define ECHUNK 2048        // edges per chunk
#define NCHUNKP 1024       // padded chunk count (real = 782)

__device__ inline ushort f2bf(float f) {            // round-to-nearest-even
    unsigned u = __float_as_uint(f);
    unsigned r = u + 0x7FFFu + ((u >> 16) & 1u);
    return (ushort)(r >> 16);
}
__device__ inline float bf2f(ushort h) {
    return __uint_as_float(((unsigned)h) << 16);
}
__device__ inline float bfu(unsigned long long v, int k) {   // bf16 lane k of u64
    return __uint_as_float((unsigned)((v >> (k * 16)) & 0xFFFFu) << 16);
}

// Per-chunk histogram over bins (LDS atomics only). gcounts layout: [bin][chunk].
__global__ __launch_bounds__(256) void k_hist(const int* __restrict__ dst,
                                              int* __restrict__ gcounts) {
    __shared__ int hist[NBINP];
    int tid = threadIdx.x, chunk = blockIdx.x;
    for (int j = tid; j < NBINP; j += 256) hist[j] = 0;
    __syncthreads();
    int base = chunk * ECHUNK;
    int lim = min(base + ECHUNK, NE);
    for (int i = base + tid; i < lim; i += 256)
        atomicAdd(&hist[dst[i] >> 7], 1);
    __syncthreads();
    for (int j = tid; j < NBINP; j += 256)
        gcounts[j * NCHUNKP + chunk] = hist[j];
}

// Per-bin exclusive scan over the chunk axis (row-contiguous, in place).
__global__ __launch_bounds__(256) void k_colscan(int* __restrict__ gcounts,
                                                 int* __restrict__ bintot) {
    __shared__ int sd[256];
    int t = threadIdx.x;
    int* p = gcounts + blockIdx.x * NCHUNKP;
    int v[4], s = 0;
    #pragma unroll
    for (int i = 0; i < 4; i++) { v[i] = p[t * 4 + i]; s += v[i]; }
    sd[t] = s;
    __syncthreads();
    for (int off = 1; off < 256; off <<= 1) {
        int x = (t >= off) ? sd[t - off] : 0;
        __syncthreads();
        sd[t] += x;
        __syncthreads();
    }
    int excl = sd[t] - s;
    #pragma unroll
    for (int i = 0; i < 4; i++) { p[t * 4 + i] = excl; excl += v[i]; }
    if (t == 255) bintot[blockIdx.x] = sd[255];
}

// Exclusive scan of 1024 bin totals -> binbase; also row_ptr[NN] = NE.
__global__ __launch_bounds__(256) void k_binscan(const int* __restrict__ bintot,
                                                 int* __restrict__ binbase,
                                                 int* __restrict__ row_ptr) {
    __shared__ int sd[256];
    int t = threadIdx.x;
    int v[4], s = 0;
    #pragma unroll
    for (int i = 0; i < 4; i++) { v[i] = bintot[t * 4 + i]; s += v[i]; }
    sd[t] = s;
    __syncthreads();
    for (int off = 1; off < 256; off <<= 1) {
        int x = (t >= off) ? sd[t - off] : 0;
        __syncthreads();
        sd[t] += x;
        __syncthreads();
    }
    int excl = sd[t] - s;
    #pragma unroll
    for (int i = 0; i < 4; i++) { binbase[t * 4 + i] = excl; excl += v[i]; }
    if (t == 255) { binbase[NBINP] = sd[255]; row_ptr[NN] = sd[255]; }
}

// Stable scatter of edges into their bin's contiguous range. No global atomics.
// meta = src (17b) | dst_local (7b) << 17
__global__ __launch_bounds__(256) void k_scatbin(const int* __restrict__ src,
                                                 const int* __restrict__ dst,
                                                 const float* __restrict__ w,
                                                 const int* __restrict__ gcounts,
                                                 const int* __restrict__ binbase,
                                                 int2* __restrict__ binned) {
    __shared__ int lcur[NBINP];
    int tid = threadIdx.x, chunk = blockIdx.x;
    for (int j = tid; j < NBINP; j += 256) lcur[j] = 0;
    __syncthreads();
    int base = chunk * ECHUNK;
    int lim = min(base + ECHUNK, NE);
    for (int i = base + tid; i < lim; i += 256) {
        int d = dst[i];
        int b = d >> 7;
        int r = atomicAdd(&lcur[b], 1);                       // LDS atomic
        int pos = binbase[b] + gcounts[b * NCHUNKP + chunk] + r;
        int meta = src[i] | ((d & 127) << 17);
        binned[pos] = make_int2(meta, __float_as_int(w[i]));
    }
}

// Per-bin: exact per-node grouping + row_ptr + dinv. All LDS-local, contiguous I/O.
__global__ __launch_bounds__(256) void k_group(const int2* __restrict__ binned,
                                               const int* __restrict__ binbase,
                                               int2* __restrict__ edata,
                                               int* __restrict__ row_ptr,
                                               float* __restrict__ dinv) {
    __shared__ int ndeg[NPB];
    __shared__ float nws[NPB];
    __shared__ int ncur[NPB];
    __shared__ int sd[NPB];
    int t = threadIdx.x, bin = blockIdx.x;
    int beg = binbase[bin], end = binbase[bin + 1];
    if (t < NPB) { ndeg[t] = 0; nws[t] = 0.f; }
    __syncthreads();
    for (int e = beg + t; e < end; e += 256) {
        int2 v = binned[e];
        int dl = ((unsigned)v.x) >> 17;
        atomicAdd(&ndeg[dl], 1);
        atomicAdd(&nws[dl], __int_as_float(v.y));
    }
    __syncthreads();
    int own = 0;
    if (t < NPB) { own = ndeg[t]; sd[t] = own; }
    __syncthreads();
    for (int off = 1; off < NPB; off <<= 1) {
        int x = (t >= off && t < NPB) ? sd[t - off] : 0;
        __syncthreads();
        if (t < NPB) sd[t] += x;
        __syncthreads();
    }
    if (t < NPB) {
        int excl = sd[t] - own;
        ncur[t] = excl;
        int node = bin * NPB + t;
        if (node < NN) {
            row_ptr[node] = beg + excl;
            dinv[node] = rsqrtf(1.0f + nws[t]);
        }
    }
    __syncthreads();
    for (int e = beg + t; e < end; e += 256) {
        int2 v = binned[e];
        int dl = ((unsigned)v.x) >> 17;
        int r = atomicAdd(&ncur[dl], 1);
        edata[beg + r] = make_int2(v.x & 0x1FFFF, v.y);   // y = raw w
    }
}

// Convert fp32 input to PRE-SCALED bf16 gather table: t[i] = dinv[i] * x[i].
__global__ __launch_bounds__(256) void k_cvt(const float* __restrict__ in,
                                             const float* __restrict__ dinv,
                                             ushort* __restrict__ outb, int total4) {
    int i = blockIdx.x * 256 + threadIdx.x;
    if (i < total4) {
        float dn = dinv[i >> 4];   // 16 float4 per row
        float4 v = reinterpret_cast<const float4*>(in)[i];
        ushort4 o;
        o.x = f2bf(v.x * dn); o.y = f2bf(v.y * dn);
        o.z = f2bf(v.z * dn); o.w = f2bf(v.w * dn);
        reinterpret_cast<ushort4*>(outb)[i] = o;
    }
}

#define FMA4U(acc, nm, q) \
    acc.x = fmaf(nm, bfu(q, 0), acc.x); acc.y = fmaf(nm, bfu(q, 1), acc.y); \
    acc.z = fmaf(nm, bfu(q, 2), acc.z); acc.w = fmaf(nm, bfu(q, 3), acc.w);

// Non-temporal 8B bf16x4 row-slice gather (bypass/early-evict L1: zero reuse).
#define NTROW(idx) __builtin_nontemporal_load( \
    reinterpret_cast<const unsigned long long*>(Hb + ((size_t)(idx) << 6) + (l << 2)))

// Fused layer. ONE NODE PER 16-LANE GROUP (4 consecutive nodes per wave).
// Table Hb is PRE-SCALED: t[s] = dinv[s]*A[s]. edata.y = raw w.
// row = (sum_e w*t[s] + t[self]) * dinv[node]; out = row@W + b (+relu);
// RELU layers store bf16 pre-scaled (dinv*relu), final layer stores fp32 raw.
template <int RELU>
__global__ __launch_bounds__(256, 8) void k_layer(const int* __restrict__ row_ptr,
                                                  const int2* __restrict__ edata,
                                                  const ushort* __restrict__ Hb,
                                                  const float* __restrict__ W,
                                                  const float* __restrict__ bias,
                                                  const float* __restrict__ dinv,
                                                  ushort* __restrict__ OutB,
                                                  float* __restrict__ OutF, int n) {
    __shared__ float Wlds[64][64];       // 16 KB
    __shared__ float rowbuf[4][4][64];   // [wave][group/node][ch] 4 KB
    int tid = threadIdx.x;
    #pragma unroll
    for (int t = tid; t < 4096; t += 256) Wlds[t >> 6][t & 63] = W[t];
    __syncthreads();

    int lane = tid & 63, wv = tid >> 6;
    int g = lane >> 4, l = lane & 15;
    float bl = bias[lane];

    int wave_id = blockIdx.x * 4 + wv;
    int nwaves = gridDim.x * 4;

    for (int base = wave_id * 4; base < n; base += nwaves * 4) {
        int node = base + g;
        bool valid = node < n;
        int beg = 0, end = 0;
        float dn = 0.f;
        if (valid) { beg = row_ptr[node]; end = row_ptr[node + 1]; dn = dinv[node]; }
        // self-row (pre-scaled) issued early
        unsigned long long svq = NTROW(valid ? node : 0);

        float4 acc = make_float4(0.f, 0.f, 0.f, 0.f);
        int e = beg;
        for (; e + 7 < end; e += 8) {          // 8 gathers in flight per group
            int2 ev[8];
            unsigned long long q[8];
            #pragma unroll
            for (int u = 0; u < 8; u++) ev[u] = edata[e + u];
            #pragma unroll
            for (int u = 0; u < 8; u++) q[u] = NTROW(ev[u].x);
            #pragma unroll
            for (int u = 0; u < 8; u++) {
                float nm = __int_as_float(ev[u].y);
                FMA4U(acc, nm, q[u]);
            }
        }
        if (e + 3 < end) {
            int2 ev[4];
            unsigned long long q[4];
            #pragma unroll
            for (int u = 0; u < 4; u++) ev[u] = edata[e + u];
            #pragma unroll
            for (int u = 0; u < 4; u++) q[u] = NTROW(ev[u].x);
            #pragma unroll
            for (int u = 0; u < 4; u++) {
                float nm = __int_as_float(ev[u].y);
                FMA4U(acc, nm, q[u]);
            }
            e += 4;
        }
        if (e + 1 < end) {
            int2 e0 = edata[e], e1 = edata[e + 1];
            unsigned long long q0 = NTROW(e0.x), q1 = NTROW(e1.x);
            float n0 = __int_as_float(e0.y), n1 = __int_as_float(e1.y);
            FMA4U(acc, n0, q0); FMA4U(acc, n1, q1);
            e += 2;
        }
        if (e < end) {
            int2 e0 = edata[e];
            unsigned long long q0 = NTROW(e0.x);
            float n0 = __int_as_float(e0.y);
            FMA4U(acc, n0, q0);
        }

        // self-loop (table pre-scaled: add t[self], then scale whole row by dn)
        acc.x = (acc.x + bfu(svq, 0)) * dn;
        acc.y = (acc.y + bfu(svq, 1)) * dn;
        acc.z = (acc.z + bfu(svq, 2)) * dn;
        acc.w = (acc.w + bfu(svq, 3)) * dn;
        *reinterpret_cast<float4*>(&rowbuf[wv][g][l * 4]) = acc;
        __builtin_amdgcn_wave_barrier();

        // epilogue: 4 nodes sequentially; rowbuf reads broadcast, Wlds conflict-free
        #pragma unroll 1
        for (int j = 0; j < 4; j++) {
            int onode = base + j;
            if (onode >= n) break;
            float o = 0.f;
            #pragma unroll
            for (int k = 0; k < 64; k++)
                o = fmaf(rowbuf[wv][j][k], Wlds[k][lane], o);
            o += bl;
            if (RELU) {
                o = fmaxf(o, 0.f);
                OutB[(size_t)onode * DIM + lane] = f2bf(o * dinv[onode]);
            } else {
                OutF[(size_t)onode * DIM + lane] = o;
            }
        }
        __builtin_amdgcn_wave_barrier();
    }
}

extern "C" void kernel_launch(void* const* d_in, const int* in_sizes, int n_in,
                              void* d_out, int out_size, void* d_ws, size_t ws_size,
                              hipStream_t stream) {
    const float* x  = (const float*)d_in[0];
    const int* ei   = (const int*)d_in[1];   // [2][NE] int32
    const float* ew = (const float*)d_in[2];
    const float* W1 = (const float*)d_in[3];
    const float* b1 = (const float*)d_in[4];
    const float* W2 = (const float*)d_in[5];
    const float* b2 = (const float*)d_in[6];
    const float* W3 = (const float*)d_in[7];
    const float* b3 = (const float*)d_in[8];
    float* out = (float*)d_out;

    const int* src = ei;
    const int* dst = ei + NE;

    auto align = [](size_t v) { return (v + 255) / 256 * 256; };
    char* ws = (char*)d_ws;
    // persistent through layers:
    int*   row_ptr = (int*)ws;   ws += align(((size_t)NN + 1) * 4);
    float* dinv    = (float*)ws; ws += align((size_t)NN * 4);
    int2*  edata   = (int2*)ws;  ws += align((size_t)NE * 8);              // 12.8 MB
    // build temporaries, later overlaid by Hb0 (all dead after k_group):
    char* temp = ws;
    int*  gcounts = (int*)temp;                 // 4 MB
    int*  bintot  = (int*)(temp + align((size_t)NBINP * NCHUNKP * 4));
    int*  binbase = (int*)((char*)bintot + align((size_t)NBINP * 4));
    int2* binned  = (int2*)((char*)binbase + align(((size_t)NBINP + 1) * 4)); // 12.8 MB
    ws += align((size_t)NBINP * NCHUNKP * 4) + align((size_t)NBINP * 4)
        + align(((size_t)NBINP + 1) * 4) + align((size_t)NE * 8);
    ushort* Hb0 = (ushort*)temp;                // 12.8 MB, overlays dead build temps
    // bf16 activations (pre-scaled by dinv):
    ushort* A1b = (ushort*)ws; ws += align((size_t)NN * DIM * 2);          // 12.8 MB
    ushort* A2b = (ushort*)ws;                                             // 12.8 MB

    const int gC = (NN * DIM / 4 + 255) / 256;
    const int gL = 2048;

    // ---- deterministic CSR build: zero global atomics ----
    k_hist<<<NCHUNKP, 256, 0, stream>>>(dst, gcounts);
    k_colscan<<<NBINP, 256, 0, stream>>>(gcounts, bintot);
    k_binscan<<<1, 256, 0, stream>>>(bintot, binbase, row_ptr);
    k_scatbin<<<NCHUNKP, 256, 0, stream>>>(src, dst, ew, gcounts, binbase, binned);
    k_group<<<NBIN, 256, 0, stream>>>(binned, binbase, edata, row_ptr, dinv);
    k_cvt<<<gC, 256, 0, stream>>>(x, dinv, Hb0, NN * DIM / 4);  // after k_group (overlay)

    // ---- fused layers: pre-scaled bf16 tables, fp32 math ----
    k_layer<1><<<gL, 256, 0, stream>>>(row_ptr, edata, Hb0, W1, b1, dinv, A1b, nullptr, NN);
    k_layer<1><<<gL, 256, 0, stream>>>(row_ptr, edata, A1b, W2, b2, dinv, A2b, nullptr, NN);
    k_layer<0><<<gL, 256, 0, stream>>>(row_ptr, edata, A2b, W3, b3, dinv, nullptr, out, NN);
}

// Round 13
// 243.230 us; speedup vs baseline: 9.0539x; 1.1778x over previous
//
#include <hip/hip_runtime.h>

#define NN 100000
#define NE 1600000
#define DIM 64
#define NPB 128            // nodes per bin
#define NBIN 782           // ceil(NN / NPB)
#define NBINP 1024         // padded for scans
#define ECHUNK 2048        // edges per chunk
#define NCHUNKP 1024       // padded chunk count (real = 782)

__device__ inline ushort f2bf(float f) {            // round-to-nearest-even
    unsigned u = __float_as_uint(f);
    unsigned r = u + 0x7FFFu + ((u >> 16) & 1u);
    return (ushort)(r >> 16);
}
__device__ inline float bf2f(ushort h) {
    return __uint_as_float(((unsigned)h) << 16);
}
__device__ inline float bfu(unsigned long long v, int k) {   // bf16 lane k of u64
    return __uint_as_float((unsigned)((v >> (k * 16)) & 0xFFFFu) << 16);
}

// Per-chunk histogram over bins (LDS atomics only). gcounts layout: [bin][chunk].
__global__ __launch_bounds__(256) void k_hist(const int* __restrict__ dst,
                                              int* __restrict__ gcounts) {
    __shared__ int hist[NBINP];
    int tid = threadIdx.x, chunk = blockIdx.x;
    for (int j = tid; j < NBINP; j += 256) hist[j] = 0;
    __syncthreads();
    int base = chunk * ECHUNK;
    int lim = min(base + ECHUNK, NE);
    for (int i = base + tid; i < lim; i += 256)
        atomicAdd(&hist[dst[i] >> 7], 1);
    __syncthreads();
    for (int j = tid; j < NBINP; j += 256)
        gcounts[j * NCHUNKP + chunk] = hist[j];
}

// Per-bin exclusive scan over the chunk axis (row-contiguous, in place).
__global__ __launch_bounds__(256) void k_colscan(int* __restrict__ gcounts,
                                                 int* __restrict__ bintot) {
    __shared__ int sd[256];
    int t = threadIdx.x;
    int* p = gcounts + blockIdx.x * NCHUNKP;
    int v[4], s = 0;
    #pragma unroll
    for (int i = 0; i < 4; i++) { v[i] = p[t * 4 + i]; s += v[i]; }
    sd[t] = s;
    __syncthreads();
    for (int off = 1; off < 256; off <<= 1) {
        int x = (t >= off) ? sd[t - off] : 0;
        __syncthreads();
        sd[t] += x;
        __syncthreads();
    }
    int excl = sd[t] - s;
    #pragma unroll
    for (int i = 0; i < 4; i++) { p[t * 4 + i] = excl; excl += v[i]; }
    if (t == 255) bintot[blockIdx.x] = sd[255];
}

// Exclusive scan of 1024 bin totals -> binbase; also row_ptr[NN] = NE.
__global__ __launch_bounds__(256) void k_binscan(const int* __restrict__ bintot,
                                                 int* __restrict__ binbase,
                                                 int* __restrict__ row_ptr) {
    __shared__ int sd[256];
    int t = threadIdx.x;
    int v[4], s = 0;
    #pragma unroll
    for (int i = 0; i < 4; i++) { v[i] = bintot[t * 4 + i]; s += v[i]; }
    sd[t] = s;
    __syncthreads();
    for (int off = 1; off < 256; off <<= 1) {
        int x = (t >= off) ? sd[t - off] : 0;
        __syncthreads();
        sd[t] += x;
        __syncthreads();
    }
    int excl = sd[t] - s;
    #pragma unroll
    for (int i = 0; i < 4; i++) { binbase[t * 4 + i] = excl; excl += v[i]; }
    if (t == 255) { binbase[NBINP] = sd[255]; row_ptr[NN] = sd[255]; }
}

// Stable scatter of edges into their bin's contiguous range. No global atomics.
// meta = src (17b) | dst_local (7b) << 17
__global__ __launch_bounds__(256) void k_scatbin(const int* __restrict__ src,
                                                 const int* __restrict__ dst,
                                                 const float* __restrict__ w,
                                                 const int* __restrict__ gcounts,
                                                 const int* __restrict__ binbase,
                                                 int2* __restrict__ binned) {
    __shared__ int lcur[NBINP];
    int tid = threadIdx.x, chunk = blockIdx.x;
    for (int j = tid; j < NBINP; j += 256) lcur[j] = 0;
    __syncthreads();
    int base = chunk * ECHUNK;
    int lim = min(base + ECHUNK, NE);
    for (int i = base + tid; i < lim; i += 256) {
        int d = dst[i];
        int b = d >> 7;
        int r = atomicAdd(&lcur[b], 1);                       // LDS atomic
        int pos = binbase[b] + gcounts[b * NCHUNKP + chunk] + r;
        int meta = src[i] | ((d & 127) << 17);
        binned[pos] = make_int2(meta, __float_as_int(w[i]));
    }
}

// Per-bin: exact per-node grouping + row_ptr + dinv. All LDS-local, contiguous I/O.
__global__ __launch_bounds__(256) void k_group(const int2* __restrict__ binned,
                                               const int* __restrict__ binbase,
                                               int2* __restrict__ edata,
                                               int* __restrict__ row_ptr,
                                               float* __restrict__ dinv) {
    __shared__ int ndeg[NPB];
    __shared__ float nws[NPB];
    __shared__ int ncur[NPB];
    __shared__ int sd[NPB];
    int t = threadIdx.x, bin = blockIdx.x;
    int beg = binbase[bin], end = binbase[bin + 1];
    if (t < NPB) { ndeg[t] = 0; nws[t] = 0.f; }
    __syncthreads();
    for (int e = beg + t; e < end; e += 256) {
        int2 v = binned[e];
        int dl = ((unsigned)v.x) >> 17;
        atomicAdd(&ndeg[dl], 1);
        atomicAdd(&nws[dl], __int_as_float(v.y));
    }
    __syncthreads();
    int own = 0;
    if (t < NPB) { own = ndeg[t]; sd[t] = own; }
    __syncthreads();
    for (int off = 1; off < NPB; off <<= 1) {
        int x = (t >= off && t < NPB) ? sd[t - off] : 0;
        __syncthreads();
        if (t < NPB) sd[t] += x;
        __syncthreads();
    }
    if (t < NPB) {
        int excl = sd[t] - own;
        ncur[t] = excl;
        int node = bin * NPB + t;
        if (node < NN) {
            row_ptr[node] = beg + excl;
            dinv[node] = rsqrtf(1.0f + nws[t]);
        }
    }
    __syncthreads();
    for (int e = beg + t; e < end; e += 256) {
        int2 v = binned[e];
        int dl = ((unsigned)v.x) >> 17;
        int r = atomicAdd(&ncur[dl], 1);
        edata[beg + r] = make_int2(v.x & 0x1FFFF, v.y);   // y = raw w
    }
}

// Convert fp32 input to PRE-SCALED bf16 gather table: t[i] = dinv[i] * x[i].
__global__ __launch_bounds__(256) void k_cvt(const float* __restrict__ in,
                                             const float* __restrict__ dinv,
                                             ushort* __restrict__ outb, int total4) {
    int i = blockIdx.x * 256 + threadIdx.x;
    if (i < total4) {
        float dn = dinv[i >> 4];   // 16 float4 per row
        float4 v = reinterpret_cast<const float4*>(in)[i];
        ushort4 o;
        o.x = f2bf(v.x * dn); o.y = f2bf(v.y * dn);
        o.z = f2bf(v.z * dn); o.w = f2bf(v.w * dn);
        reinterpret_cast<ushort4*>(outb)[i] = o;
    }
}

#define FMA4U(acc, nm, q) \
    acc.x = fmaf(nm, bfu(q, 0), acc.x); acc.y = fmaf(nm, bfu(q, 1), acc.y); \
    acc.z = fmaf(nm, bfu(q, 2), acc.z); acc.w = fmaf(nm, bfu(q, 3), acc.w);

// Plain (cached) 8B bf16x4 row-slice gather — L1/L2 retention helps (r12 lesson:
// nontemporal hints raised FETCH_SIZE 87->105 MB and cost +9us/layer).
#define LDROW(idx) (*reinterpret_cast<const unsigned long long*>( \
    Hb + ((size_t)(idx) << 6) + (l << 2)))

// Fused layer. ONE NODE PER 16-LANE GROUP (4 consecutive nodes per wave).
// Table Hb is PRE-SCALED: t[s] = dinv[s]*A[s]. edata.y = raw w.
// row = (sum_e w*t[s] + t[self]) * dinv[node]; out = row@W + b (+relu);
// RELU layers store bf16 pre-scaled (dinv*relu), final layer stores fp32 raw.
template <int RELU>
__global__ __launch_bounds__(256, 8) void k_layer(const int* __restrict__ row_ptr,
                                                  const int2* __restrict__ edata,
                                                  const ushort* __restrict__ Hb,
                                                  const float* __restrict__ W,
                                                  const float* __restrict__ bias,
                                                  const float* __restrict__ dinv,
                                                  ushort* __restrict__ OutB,
                                                  float* __restrict__ OutF, int n) {
    __shared__ float Wlds[64][64];       // 16 KB
    __shared__ float rowbuf[4][4][64];   // [wave][group/node][ch] 4 KB
    int tid = threadIdx.x;
    #pragma unroll
    for (int t = tid; t < 4096; t += 256) Wlds[t >> 6][t & 63] = W[t];
    __syncthreads();

    int lane = tid & 63, wv = tid >> 6;
    int g = lane >> 4, l = lane & 15;
    float bl = bias[lane];

    int wave_id = blockIdx.x * 4 + wv;
    int nwaves = gridDim.x * 4;

    for (int base = wave_id * 4; base < n; base += nwaves * 4) {
        int node = base + g;
        bool valid = node < n;
        int beg = 0, end = 0;
        float dn = 0.f;
        if (valid) { beg = row_ptr[node]; end = row_ptr[node + 1]; dn = dinv[node]; }
        // self-row (pre-scaled) issued early
        unsigned long long svq = LDROW(valid ? node : 0);

        float4 acc = make_float4(0.f, 0.f, 0.f, 0.f);
        int e = beg;
        for (; e + 7 < end; e += 8) {          // 8 gathers in flight per group
            int2 ev[8];
            unsigned long long q[8];
            #pragma unroll
            for (int u = 0; u < 8; u++) ev[u] = edata[e + u];
            #pragma unroll
            for (int u = 0; u < 8; u++) q[u] = LDROW(ev[u].x);
            #pragma unroll
            for (int u = 0; u < 8; u++) {
                float nm = __int_as_float(ev[u].y);
                FMA4U(acc, nm, q[u]);
            }
        }
        if (e + 3 < end) {
            int2 ev[4];
            unsigned long long q[4];
            #pragma unroll
            for (int u = 0; u < 4; u++) ev[u] = edata[e + u];
            #pragma unroll
            for (int u = 0; u < 4; u++) q[u] = LDROW(ev[u].x);
            #pragma unroll
            for (int u = 0; u < 4; u++) {
                float nm = __int_as_float(ev[u].y);
                FMA4U(acc, nm, q[u]);
            }
            e += 4;
        }
        if (e + 1 < end) {
            int2 e0 = edata[e], e1 = edata[e + 1];
            unsigned long long q0 = LDROW(e0.x), q1 = LDROW(e1.x);
            float n0 = __int_as_float(e0.y), n1 = __int_as_float(e1.y);
            FMA4U(acc, n0, q0); FMA4U(acc, n1, q1);
            e += 2;
        }
        if (e < end) {
            int2 e0 = edata[e];
            unsigned long long q0 = LDROW(e0.x);
            float n0 = __int_as_float(e0.y);
            FMA4U(acc, n0, q0);
        }

        // self-loop (table pre-scaled: add t[self], then scale whole row by dn)
        acc.x = (acc.x + bfu(svq, 0)) * dn;
        acc.y = (acc.y + bfu(svq, 1)) * dn;
        acc.z = (acc.z + bfu(svq, 2)) * dn;
        acc.w = (acc.w + bfu(svq, 3)) * dn;
        *reinterpret_cast<float4*>(&rowbuf[wv][g][l * 4]) = acc;
        __builtin_amdgcn_wave_barrier();

        // epilogue: 4 nodes sequentially; rowbuf reads broadcast, Wlds conflict-free
        #pragma unroll 1
        for (int j = 0; j < 4; j++) {
            int onode = base + j;
            if (onode >= n) break;
            float o = 0.f;
            #pragma unroll
            for (int k = 0; k < 64; k++)
                o = fmaf(rowbuf[wv][j][k], Wlds[k][lane], o);
            o += bl;
            if (RELU) {
                o = fmaxf(o, 0.f);
                OutB[(size_t)onode * DIM + lane] = f2bf(o * dinv[onode]);
            } else {
                OutF[(size_t)onode * DIM + lane] = o;
            }
        }
        __builtin_amdgcn_wave_barrier();
    }
}

extern "C" void kernel_launch(void* const* d_in, const int* in_sizes, int n_in,
                              void* d_out, int out_size, void* d_ws, size_t ws_size,
                              hipStream_t stream) {
    const float* x  = (const float*)d_in[0];
    const int* ei   = (const int*)d_in[1];   // [2][NE] int32
    const float* ew = (const float*)d_in[2];
    const float* W1 = (const float*)d_in[3];
    const float* b1 = (const float*)d_in[4];
    const float* W2 = (const float*)d_in[5];
    const float* b2 = (const float*)d_in[6];
    const float* W3 = (const float*)d_in[7];
    const float* b3 = (const float*)d_in[8];
    float* out = (float*)d_out;

    const int* src = ei;
    const int* dst = ei + NE;

    auto align = [](size_t v) { return (v + 255) / 256 * 256; };
    char* ws = (char*)d_ws;
    // persistent through layers:
    int*   row_ptr = (int*)ws;   ws += align(((size_t)NN + 1) * 4);
    float* dinv    = (float*)ws; ws += align((size_t)NN * 4);
    int2*  edata   = (int2*)ws;  ws += align((size_t)NE * 8);              // 12.8 MB
    // build temporaries, later overlaid by Hb0 (all dead after k_group):
    char* temp = ws;
    int*  gcounts = (int*)temp;                 // 4 MB
    int*  bintot  = (int*)(temp + align((size_t)NBINP * NCHUNKP * 4));
    int*  binbase = (int*)((char*)bintot + align((size_t)NBINP * 4));
    int2* binned  = (int2*)((char*)binbase + align(((size_t)NBINP + 1) * 4)); // 12.8 MB
    ws += align((size_t)NBINP * NCHUNKP * 4) + align((size_t)NBINP * 4)
        + align(((size_t)NBINP + 1) * 4) + align((size_t)NE * 8);
    ushort* Hb0 = (ushort*)temp;                // 12.8 MB, overlays dead build temps
    // bf16 activations (pre-scaled by dinv):
    ushort* A1b = (ushort*)ws; ws += align((size_t)NN * DIM * 2);          // 12.8 MB
    ushort* A2b = (ushort*)ws;                                             // 12.8 MB

    const int gC = (NN * DIM / 4 + 255) / 256;
    const int gL = 2048;

    // ---- deterministic CSR build: zero global atomics ----
    k_hist<<<NCHUNKP, 256, 0, stream>>>(dst, gcounts);
    k_colscan<<<NBINP, 256, 0, stream>>>(gcounts, bintot);
    k_binscan<<<1, 256, 0, stream>>>(bintot, binbase, row_ptr);
    k_scatbin<<<NCHUNKP, 256, 0, stream>>>(src, dst, ew, gcounts, binbase, binned);
    k_group<<<NBIN, 256, 0, stream>>>(binned, binbase, edata, row_ptr, dinv);
    k_cvt<<<gC, 256, 0, stream>>>(x, dinv, Hb0, NN * DIM / 4);  // after k_group (overlay)

    // ---- fused layers: pre-scaled bf16 tables, fp32 math ----
    k_layer<1><<<gL, 256, 0, stream>>>(row_ptr, edata, Hb0, W1, b1, dinv, A1b, nullptr, NN);
    k_layer<1><<<gL, 256, 0, stream>>>(row_ptr, edata, A1b, W2, b2, dinv, A2b, nullptr, NN);
    k_layer<0><<<gL, 256, 0, stream>>>(row_ptr, edata, A2b, W3, b3, dinv, nullptr, out, NN);
}

// Round 14
// 233.743 us; speedup vs baseline: 9.4214x; 1.0406x over previous
//
#include <hip/hip_runtime.h>

#define NN 100000
#define NE 1600000
#define DIM 64
#define NPB 128            // nodes per bin
#define NBIN 782           // ceil(NN / NPB)
#define NBINP 1024         // padded for scans
#define ECHUNK 2048        // edges per chunk
#define NCHUNKP 1024       // padded chunk count (real = 782)

__device__ inline ushort f2bf(float f) {            // round-to-nearest-even
    unsigned u = __float_as_uint(f);
    unsigned r = u + 0x7FFFu + ((u >> 16) & 1u);
    return (ushort)(r >> 16);
}
__device__ inline float bfu(unsigned long long v, int k) {   // bf16 lane k of u64
    return __uint_as_float((unsigned)((v >> (k * 16)) & 0xFFFFu) << 16);
}

// Per-chunk histogram over bins (LDS atomics only). gcounts layout: [bin][chunk].
__global__ __launch_bounds__(256) void k_hist(const int* __restrict__ dst,
                                              int* __restrict__ gcounts) {
    __shared__ int hist[NBINP];
    int tid = threadIdx.x, chunk = blockIdx.x;
    for (int j = tid; j < NBINP; j += 256) hist[j] = 0;
    __syncthreads();
    int base = chunk * ECHUNK;
    int lim = min(base + ECHUNK, NE);
    for (int i = base + tid; i < lim; i += 256)
        atomicAdd(&hist[dst[i] >> 7], 1);
    __syncthreads();
    for (int j = tid; j < NBINP; j += 256)
        gcounts[j * NCHUNKP + chunk] = hist[j];
}

// Per-bin exclusive scan over the chunk axis (row-contiguous, in place).
__global__ __launch_bounds__(256) void k_colscan(int* __restrict__ gcounts,
                                                 int* __restrict__ bintot) {
    __shared__ int sd[256];
    int t = threadIdx.x;
    int* p = gcounts + blockIdx.x * NCHUNKP;
    int v[4], s = 0;
    #pragma unroll
    for (int i = 0; i < 4; i++) { v[i] = p[t * 4 + i]; s += v[i]; }
    sd[t] = s;
    __syncthreads();
    for (int off = 1; off < 256; off <<= 1) {
        int x = (t >= off) ? sd[t - off] : 0;
        __syncthreads();
        sd[t] += x;
        __syncthreads();
    }
    int excl = sd[t] - s;
    #pragma unroll
    for (int i = 0; i < 4; i++) { p[t * 4 + i] = excl; excl += v[i]; }
    if (t == 255) bintot[blockIdx.x] = sd[255];
}

// Exclusive scan of 1024 bin totals -> binbase; also row_ptr[NN] = NE.
__global__ __launch_bounds__(256) void k_binscan(const int* __restrict__ bintot,
                                                 int* __restrict__ binbase,
                                                 int* __restrict__ row_ptr) {
    __shared__ int sd[256];
    int t = threadIdx.x;
    int v[4], s = 0;
    #pragma unroll
    for (int i = 0; i < 4; i++) { v[i] = bintot[t * 4 + i]; s += v[i]; }
    sd[t] = s;
    __syncthreads();
    for (int off = 1; off < 256; off <<= 1) {
        int x = (t >= off) ? sd[t - off] : 0;
        __syncthreads();
        sd[t] += x;
        __syncthreads();
    }
    int excl = sd[t] - s;
    #pragma unroll
    for (int i = 0; i < 4; i++) { binbase[t * 4 + i] = excl; excl += v[i]; }
    if (t == 255) { binbase[NBINP] = sd[255]; row_ptr[NN] = sd[255]; }
}

// Stable scatter of edges into their bin's contiguous range. No global atomics.
// meta = src (17b) | dst_local (7b) << 17
__global__ __launch_bounds__(256) void k_scatbin(const int* __restrict__ src,
                                                 const int* __restrict__ dst,
                                                 const float* __restrict__ w,
                                                 const int* __restrict__ gcounts,
                                                 const int* __restrict__ binbase,
                                                 int2* __restrict__ binned) {
    __shared__ int lcur[NBINP];
    int tid = threadIdx.x, chunk = blockIdx.x;
    for (int j = tid; j < NBINP; j += 256) lcur[j] = 0;
    __syncthreads();
    int base = chunk * ECHUNK;
    int lim = min(base + ECHUNK, NE);
    for (int i = base + tid; i < lim; i += 256) {
        int d = dst[i];
        int b = d >> 7;
        int r = atomicAdd(&lcur[b], 1);                       // LDS atomic
        int pos = binbase[b] + gcounts[b * NCHUNKP + chunk] + r;
        int meta = src[i] | ((d & 127) << 17);
        binned[pos] = make_int2(meta, __float_as_int(w[i]));
    }
}

// Per-bin: per-node grouping + row_ptr + dinv + PACKED edata (src<<15 | q15(w))
// + bf16 pre-scaled table conversion for this bin's 128 x-rows (k_cvt folded in).
__global__ __launch_bounds__(256) void k_group(const int2* __restrict__ binned,
                                               const int* __restrict__ binbase,
                                               const float* __restrict__ x,
                                               unsigned* __restrict__ edata,
                                               int* __restrict__ row_ptr,
                                               float* __restrict__ dinv,
                                               ushort* __restrict__ Hb0) {
    __shared__ int ndeg[NPB];
    __shared__ float nws[NPB];     // weight sums, then dinv values
    __shared__ int ncur[NPB];
    __shared__ int sd[NPB];
    int t = threadIdx.x, bin = blockIdx.x;
    int beg = binbase[bin], end = binbase[bin + 1];
    if (t < NPB) { ndeg[t] = 0; nws[t] = 0.f; }
    __syncthreads();
    for (int e = beg + t; e < end; e += 256) {
        int2 v = binned[e];
        int dl = ((unsigned)v.x) >> 17;
        atomicAdd(&ndeg[dl], 1);
        atomicAdd(&nws[dl], __int_as_float(v.y));
    }
    __syncthreads();
    int own = 0;
    if (t < NPB) { own = ndeg[t]; sd[t] = own; }
    __syncthreads();
    for (int off = 1; off < NPB; off <<= 1) {
        int xx = (t >= off && t < NPB) ? sd[t - off] : 0;
        __syncthreads();
        if (t < NPB) sd[t] += xx;
        __syncthreads();
    }
    if (t < NPB) {
        int excl = sd[t] - own;
        ncur[t] = excl;
        float dv = rsqrtf(1.0f + nws[t]);
        nws[t] = dv;                       // nws now holds dinv
        int node = bin * NPB + t;
        if (node < NN) {
            row_ptr[node] = beg + excl;
            dinv[node] = dv;
        }
    }
    __syncthreads();
    // scatter to packed per-node edata
    for (int e = beg + t; e < end; e += 256) {
        int2 v = binned[e];
        int dl = ((unsigned)v.x) >> 17;
        int r = atomicAdd(&ncur[dl], 1);
        unsigned q15 = __float2uint_rn(__int_as_float(v.y) * 32767.0f);
        edata[beg + r] = ((unsigned)(v.x & 0x1FFFF) << 15) | q15;
    }
    // bf16 pre-scaled table for this bin's rows: Hb0[node] = dinv[node]*x[node]
    int rowlim = min(NPB, NN - bin * NPB);
    for (int idx = t; idx < rowlim * 16; idx += 256) {    // 16 float4 per row
        int row = idx >> 4;
        int node = bin * NPB + row;
        float dn = nws[row];
        float4 v = reinterpret_cast<const float4*>(x)[(size_t)node * 16 + (idx & 15)];
        ushort4 o;
        o.x = f2bf(v.x * dn); o.y = f2bf(v.y * dn);
        o.z = f2bf(v.z * dn); o.w = f2bf(v.w * dn);
        reinterpret_cast<ushort4*>(Hb0)[(size_t)node * 16 + (idx & 15)] = o;
    }
}

#define FMA4U(acc, nm, q) \
    acc.x = fmaf(nm, bfu(q, 0), acc.x); acc.y = fmaf(nm, bfu(q, 1), acc.y); \
    acc.z = fmaf(nm, bfu(q, 2), acc.z); acc.w = fmaf(nm, bfu(q, 3), acc.w);

// Plain (cached) 8B bf16x4 row-slice gather — L1/L2 retention helps (r12 lesson).
#define LDROW(idx) (*reinterpret_cast<const unsigned long long*>( \
    Hb + ((size_t)(idx) << 6) + (l << 2)))
#define DEQ(v) ((float)((v) & 0x7FFFu) * (1.0f / 32767.0f))

// Fused layer. ONE NODE PER 16-LANE GROUP (4 consecutive nodes per wave).
// Table Hb is PRE-SCALED: t[s] = dinv[s]*A[s]. edata = (src<<15)|q15(w).
// row = (sum_e w*t[s] + t[self]) * dinv[node]; out = row@W + b (+relu);
// RELU layers store bf16 pre-scaled (dinv*relu), final layer stores fp32 raw.
template <int RELU>
__global__ __launch_bounds__(256, 8) void k_layer(const int* __restrict__ row_ptr,
                                                  const unsigned* __restrict__ edata,
                                                  const ushort* __restrict__ Hb,
                                                  const float* __restrict__ W,
                                                  const float* __restrict__ bias,
                                                  const float* __restrict__ dinv,
                                                  ushort* __restrict__ OutB,
                                                  float* __restrict__ OutF, int n) {
    __shared__ float Wlds[64][64];       // 16 KB
    __shared__ float rowbuf[4][4][64];   // [wave][group/node][ch] 4 KB
    int tid = threadIdx.x;
    #pragma unroll
    for (int t = tid; t < 4096; t += 256) Wlds[t >> 6][t & 63] = W[t];
    __syncthreads();

    int lane = tid & 63, wv = tid >> 6;
    int g = lane >> 4, l = lane & 15;
    float bl = bias[lane];

    int wave_id = blockIdx.x * 4 + wv;
    int nwaves = gridDim.x * 4;

    for (int base = wave_id * 4; base < n; base += nwaves * 4) {
        int node = base + g;
        bool valid = node < n;
        int beg = 0, end = 0;
        float dn = 0.f;
        if (valid) { beg = row_ptr[node]; end = row_ptr[node + 1]; dn = dinv[node]; }
        // self-row (pre-scaled) issued early
        unsigned long long svq = LDROW(valid ? node : 0);

        float4 acc = make_float4(0.f, 0.f, 0.f, 0.f);
        int e = beg;
        for (; e + 7 < end; e += 8) {          // 8 gathers in flight per group
            unsigned ev[8];
            unsigned long long q[8];
            #pragma unroll
            for (int u = 0; u < 8; u++) ev[u] = edata[e + u];
            #pragma unroll
            for (int u = 0; u < 8; u++) q[u] = LDROW(ev[u] >> 15);
            #pragma unroll
            for (int u = 0; u < 8; u++) {
                float nm = DEQ(ev[u]);
                FMA4U(acc, nm, q[u]);
            }
        }
        if (e + 3 < end) {
            unsigned ev[4];
            unsigned long long q[4];
            #pragma unroll
            for (int u = 0; u < 4; u++) ev[u] = edata[e + u];
            #pragma unroll
            for (int u = 0; u < 4; u++) q[u] = LDROW(ev[u] >> 15);
            #pragma unroll
            for (int u = 0; u < 4; u++) {
                float nm = DEQ(ev[u]);
                FMA4U(acc, nm, q[u]);
            }
            e += 4;
        }
        if (e + 1 < end) {
            unsigned e0 = edata[e], e1 = edata[e + 1];
            unsigned long long q0 = LDROW(e0 >> 15), q1 = LDROW(e1 >> 15);
            FMA4U(acc, DEQ(e0), q0); FMA4U(acc, DEQ(e1), q1);
            e += 2;
        }
        if (e < end) {
            unsigned e0 = edata[e];
            unsigned long long q0 = LDROW(e0 >> 15);
            FMA4U(acc, DEQ(e0), q0);
        }

        // self-loop (table pre-scaled: add t[self], then scale whole row by dn)
        acc.x = (acc.x + bfu(svq, 0)) * dn;
        acc.y = (acc.y + bfu(svq, 1)) * dn;
        acc.z = (acc.z + bfu(svq, 2)) * dn;
        acc.w = (acc.w + bfu(svq, 3)) * dn;
        *reinterpret_cast<float4*>(&rowbuf[wv][g][l * 4]) = acc;
        __builtin_amdgcn_wave_barrier();

        // epilogue: 4 nodes sequentially; rowbuf reads broadcast, Wlds conflict-free
        #pragma unroll 1
        for (int j = 0; j < 4; j++) {
            int onode = base + j;
            if (onode >= n) break;
            float o = 0.f;
            #pragma unroll
            for (int k = 0; k < 64; k++)
                o = fmaf(rowbuf[wv][j][k], Wlds[k][lane], o);
            o += bl;
            if (RELU) {
                o = fmaxf(o, 0.f);
                OutB[(size_t)onode * DIM + lane] = f2bf(o * dinv[onode]);
            } else {
                OutF[(size_t)onode * DIM + lane] = o;
            }
        }
        __builtin_amdgcn_wave_barrier();
    }
}

extern "C" void kernel_launch(void* const* d_in, const int* in_sizes, int n_in,
                              void* d_out, int out_size, void* d_ws, size_t ws_size,
                              hipStream_t stream) {
    const float* x  = (const float*)d_in[0];
    const int* ei   = (const int*)d_in[1];   // [2][NE] int32
    const float* ew = (const float*)d_in[2];
    const float* W1 = (const float*)d_in[3];
    const float* b1 = (const float*)d_in[4];
    const float* W2 = (const float*)d_in[5];
    const float* b2 = (const float*)d_in[6];
    const float* W3 = (const float*)d_in[7];
    const float* b3 = (const float*)d_in[8];
    float* out = (float*)d_out;

    const int* src = ei;
    const int* dst = ei + NE;

    auto align = [](size_t v) { return (v + 255) / 256 * 256; };
    char* ws = (char*)d_ws;
    // persistent:
    int*      row_ptr = (int*)ws;      ws += align(((size_t)NN + 1) * 4);
    float*    dinv    = (float*)ws;    ws += align((size_t)NN * 4);
    unsigned* edata   = (unsigned*)ws; ws += align((size_t)NE * 4);        // 6.4 MB
    ushort*   Hb0     = (ushort*)ws;   ws += align((size_t)NN * DIM * 2);  // 12.8 MB
    ushort*   A1b     = (ushort*)ws;   ws += align((size_t)NN * DIM * 2);  // 12.8 MB
    ushort*   A2b     = (ushort*)ws;   ws += align((size_t)NN * DIM * 2);  // 12.8 MB
    // build temporaries (no overlay needed):
    int*  gcounts = (int*)ws;  ws += align((size_t)NBINP * NCHUNKP * 4);   // 4 MB
    int*  bintot  = (int*)ws;  ws += align((size_t)NBINP * 4);
    int*  binbase = (int*)ws;  ws += align(((size_t)NBINP + 1) * 4);
    int2* binned  = (int2*)ws;                                             // 12.8 MB

    const int gL = 2048;

    // ---- deterministic CSR build: zero global atomics ----
    k_hist<<<NCHUNKP, 256, 0, stream>>>(dst, gcounts);
    k_colscan<<<NBINP, 256, 0, stream>>>(gcounts, bintot);
    k_binscan<<<1, 256, 0, stream>>>(bintot, binbase, row_ptr);
    k_scatbin<<<NCHUNKP, 256, 0, stream>>>(src, dst, ew, gcounts, binbase, binned);
    k_group<<<NBIN, 256, 0, stream>>>(binned, binbase, x, edata, row_ptr, dinv, Hb0);

    // ---- fused layers: pre-scaled bf16 tables, packed edges, fp32 math ----
    k_layer<1><<<gL, 256, 0, stream>>>(row_ptr, edata, Hb0, W1, b1, dinv, A1b, nullptr, NN);
    k_layer<1><<<gL, 256, 0, stream>>>(row_ptr, edata, A1b, W2, b2, dinv, A2b, nullptr, NN);
    k_layer<0><<<gL, 256, 0, stream>>>(row_ptr, edata, A2b, W3, b3, dinv, nullptr, out, NN);
}

// Round 15
// 225.186 us; speedup vs baseline: 9.7794x; 1.0380x over previous
//
#include <hip/hip_runtime.h>

#define NN 100000
#define NE 1600000
#define DIM 64
#define NPB 128            // nodes per bin
#define NBIN 782           // ceil(NN / NPB)
#define NBINP 1024         // padded for scans
#define ECHUNK 2048        // edges per chunk
#define NCHUNKP 1024       // padded chunk count (real = 782)

__device__ inline ushort f2bf(float f) {            // round-to-nearest-even
    unsigned u = __float_as_uint(f);
    unsigned r = u + 0x7FFFu + ((u >> 16) & 1u);
    return (ushort)(r >> 16);
}
__device__ inline float bfu(unsigned long long v, int k) {   // bf16 lane k of u64
    return __uint_as_float((unsigned)((v >> (k * 16)) & 0xFFFFu) << 16);
}

// Per-chunk histogram over bins (LDS atomics only). gcounts layout: [bin][chunk].
__global__ __launch_bounds__(256) void k_hist(const int* __restrict__ dst,
                                              int* __restrict__ gcounts) {
    __shared__ int hist[NBINP];
    int tid = threadIdx.x, chunk = blockIdx.x;
    for (int j = tid; j < NBINP; j += 256) hist[j] = 0;
    __syncthreads();
    int base = chunk * ECHUNK;
    int lim = min(base + ECHUNK, NE);
    for (int i = base + tid; i < lim; i += 256)
        atomicAdd(&hist[dst[i] >> 7], 1);
    __syncthreads();
    for (int j = tid; j < NBINP; j += 256)
        gcounts[j * NCHUNKP + chunk] = hist[j];
}

// Per-bin exclusive scan over the chunk axis (row-contiguous, in place).
__global__ __launch_bounds__(256) void k_colscan(int* __restrict__ gcounts,
                                                 int* __restrict__ bintot) {
    __shared__ int sd[256];
    int t = threadIdx.x;
    int* p = gcounts + blockIdx.x * NCHUNKP;
    int v[4], s = 0;
    #pragma unroll
    for (int i = 0; i < 4; i++) { v[i] = p[t * 4 + i]; s += v[i]; }
    sd[t] = s;
    __syncthreads();
    for (int off = 1; off < 256; off <<= 1) {
        int x = (t >= off) ? sd[t - off] : 0;
        __syncthreads();
        sd[t] += x;
        __syncthreads();
    }
    int excl = sd[t] - s;
    #pragma unroll
    for (int i = 0; i < 4; i++) { p[t * 4 + i] = excl; excl += v[i]; }
    if (t == 255) bintot[blockIdx.x] = sd[255];
}

// Exclusive scan of 1024 bin totals -> binbase; also row_ptr[NN] = NE.
__global__ __launch_bounds__(256) void k_binscan(const int* __restrict__ bintot,
                                                 int* __restrict__ binbase,
                                                 int* __restrict__ row_ptr) {
    __shared__ int sd[256];
    int t = threadIdx.x;
    int v[4], s = 0;
    #pragma unroll
    for (int i = 0; i < 4; i++) { v[i] = bintot[t * 4 + i]; s += v[i]; }
    sd[t] = s;
    __syncthreads();
    for (int off = 1; off < 256; off <<= 1) {
        int x = (t >= off) ? sd[t - off] : 0;
        __syncthreads();
        sd[t] += x;
        __syncthreads();
    }
    int excl = sd[t] - s;
    #pragma unroll
    for (int i = 0; i < 4; i++) { binbase[t * 4 + i] = excl; excl += v[i]; }
    if (t == 255) { binbase[NBINP] = sd[255]; row_ptr[NN] = sd[255]; }
}

// Stable scatter of edges into their bin's contiguous range. No global atomics.
// meta = src (17b) | dst_local (7b) << 17
__global__ __launch_bounds__(256) void k_scatbin(const int* __restrict__ src,
                                                 const int* __restrict__ dst,
                                                 const float* __restrict__ w,
                                                 const int* __restrict__ gcounts,
                                                 const int* __restrict__ binbase,
                                                 int2* __restrict__ binned) {
    __shared__ int lcur[NBINP];
    int tid = threadIdx.x, chunk = blockIdx.x;
    for (int j = tid; j < NBINP; j += 256) lcur[j] = 0;
    __syncthreads();
    int base = chunk * ECHUNK;
    int lim = min(base + ECHUNK, NE);
    for (int i = base + tid; i < lim; i += 256) {
        int d = dst[i];
        int b = d >> 7;
        int r = atomicAdd(&lcur[b], 1);                       // LDS atomic
        int pos = binbase[b] + gcounts[b * NCHUNKP + chunk] + r;
        int meta = src[i] | ((d & 127) << 17);
        binned[pos] = make_int2(meta, __float_as_int(w[i]));
    }
}

// Per-bin: per-node grouping + row_ptr + dinv + PACKED edata (src<<15 | q15(w))
// + bf16 pre-scaled table conversion for this bin's 128 x-rows (k_cvt folded in).
__global__ __launch_bounds__(256) void k_group(const int2* __restrict__ binned,
                                               const int* __restrict__ binbase,
                                               const float* __restrict__ x,
                                               unsigned* __restrict__ edata,
                                               int* __restrict__ row_ptr,
                                               float* __restrict__ dinv,
                                               ushort* __restrict__ Hb0) {
    __shared__ int ndeg[NPB];
    __shared__ float nws[NPB];     // weight sums, then dinv values
    __shared__ int ncur[NPB];
    __shared__ int sd[NPB];
    int t = threadIdx.x, bin = blockIdx.x;
    int beg = binbase[bin], end = binbase[bin + 1];
    if (t < NPB) { ndeg[t] = 0; nws[t] = 0.f; }
    __syncthreads();
    for (int e = beg + t; e < end; e += 256) {
        int2 v = binned[e];
        int dl = ((unsigned)v.x) >> 17;
        atomicAdd(&ndeg[dl], 1);
        atomicAdd(&nws[dl], __int_as_float(v.y));
    }
    __syncthreads();
    int own = 0;
    if (t < NPB) { own = ndeg[t]; sd[t] = own; }
    __syncthreads();
    for (int off = 1; off < NPB; off <<= 1) {
        int xx = (t >= off && t < NPB) ? sd[t - off] : 0;
        __syncthreads();
        if (t < NPB) sd[t] += xx;
        __syncthreads();
    }
    if (t < NPB) {
        int excl = sd[t] - own;
        ncur[t] = excl;
        float dv = rsqrtf(1.0f + nws[t]);
        nws[t] = dv;                       // nws now holds dinv
        int node = bin * NPB + t;
        if (node < NN) {
            row_ptr[node] = beg + excl;
            dinv[node] = dv;
        }
    }
    __syncthreads();
    // scatter to packed per-node edata
    for (int e = beg + t; e < end; e += 256) {
        int2 v = binned[e];
        int dl = ((unsigned)v.x) >> 17;
        int r = atomicAdd(&ncur[dl], 1);
        unsigned q15 = __float2uint_rn(__int_as_float(v.y) * 32767.0f);
        edata[beg + r] = ((unsigned)(v.x & 0x1FFFF) << 15) | q15;
    }
    // bf16 pre-scaled table for this bin's rows: Hb0[node] = dinv[node]*x[node]
    int rowlim = min(NPB, NN - bin * NPB);
    for (int idx = t; idx < rowlim * 16; idx += 256) {    // 16 float4 per row
        int row = idx >> 4;
        int node = bin * NPB + row;
        float dn = nws[row];
        float4 v = reinterpret_cast<const float4*>(x)[(size_t)node * 16 + (idx & 15)];
        ushort4 o;
        o.x = f2bf(v.x * dn); o.y = f2bf(v.y * dn);
        o.z = f2bf(v.z * dn); o.w = f2bf(v.w * dn);
        reinterpret_cast<ushort4*>(Hb0)[(size_t)node * 16 + (idx & 15)] = o;
    }
}

#define FMA4U(acc, nm, q) \
    acc.x = fmaf(nm, bfu(q, 0), acc.x); acc.y = fmaf(nm, bfu(q, 1), acc.y); \
    acc.z = fmaf(nm, bfu(q, 2), acc.z); acc.w = fmaf(nm, bfu(q, 3), acc.w);

// Plain (cached) 8B bf16x4 row-slice gather — L1/L2 retention helps (r12 lesson).
#define LDROW(idx) (*reinterpret_cast<const unsigned long long*>( \
    Hb + ((size_t)(idx) << 6) + (l << 2)))
#define DEQ(v) ((float)((v) & 0x7FFFu) * (1.0f / 32767.0f))

// Fused layer. ONE NODE PER 16-LANE GROUP (4 consecutive nodes per wave).
// Table Hb is PRE-SCALED: t[s] = dinv[s]*A[s]. edata = (src<<15)|q15(w).
// Epilogue: W column held in 64 VGPRs (no LDS reads for W); rowbuf read via
// uniform-address float4 broadcasts. This takes the per-node LDS-pipe cost
// from ~256 cycles to ~64 (the r14 bottleneck).
template <int RELU>
__global__ __launch_bounds__(256, 4) void k_layer(const int* __restrict__ row_ptr,
                                                  const unsigned* __restrict__ edata,
                                                  const ushort* __restrict__ Hb,
                                                  const float* __restrict__ W,
                                                  const float* __restrict__ bias,
                                                  const float* __restrict__ dinv,
                                                  ushort* __restrict__ OutB,
                                                  float* __restrict__ OutF, int n) {
    __shared__ float rowbuf[4][4][68];   // [wave][group/node][ch pad 68] 4.3 KB
    int tid = threadIdx.x;
    int lane = tid & 63, wv = tid >> 6;
    int g = lane >> 4, l = lane & 15;

    // my output column of W in registers (64 coalesced loads, static indexing)
    float wr[64];
    #pragma unroll
    for (int k = 0; k < 64; k++) wr[k] = W[k * 64 + lane];
    float bl = bias[lane];

    int wave_id = blockIdx.x * 4 + wv;
    int nwaves = gridDim.x * 4;

    for (int base = wave_id * 4; base < n; base += nwaves * 4) {
        int node = base + g;
        bool valid = node < n;
        int beg = 0, end = 0;
        float dn = 0.f;
        if (valid) { beg = row_ptr[node]; end = row_ptr[node + 1]; dn = dinv[node]; }
        // self-row (pre-scaled) issued early
        unsigned long long svq = LDROW(valid ? node : 0);

        float4 acc = make_float4(0.f, 0.f, 0.f, 0.f);
        int e = beg;
        for (; e + 7 < end; e += 8) {          // 8 gathers in flight per group
            unsigned ev[8];
            unsigned long long q[8];
            #pragma unroll
            for (int u = 0; u < 8; u++) ev[u] = edata[e + u];
            #pragma unroll
            for (int u = 0; u < 8; u++) q[u] = LDROW(ev[u] >> 15);
            #pragma unroll
            for (int u = 0; u < 8; u++) {
                float nm = DEQ(ev[u]);
                FMA4U(acc, nm, q[u]);
            }
        }
        if (e + 3 < end) {
            unsigned ev[4];
            unsigned long long q[4];
            #pragma unroll
            for (int u = 0; u < 4; u++) ev[u] = edata[e + u];
            #pragma unroll
            for (int u = 0; u < 4; u++) q[u] = LDROW(ev[u] >> 15);
            #pragma unroll
            for (int u = 0; u < 4; u++) {
                float nm = DEQ(ev[u]);
                FMA4U(acc, nm, q[u]);
            }
            e += 4;
        }
        if (e + 1 < end) {
            unsigned e0 = edata[e], e1 = edata[e + 1];
            unsigned long long q0 = LDROW(e0 >> 15), q1 = LDROW(e1 >> 15);
            FMA4U(acc, DEQ(e0), q0); FMA4U(acc, DEQ(e1), q1);
            e += 2;
        }
        if (e < end) {
            unsigned e0 = edata[e];
            unsigned long long q0 = LDROW(e0 >> 15);
            FMA4U(acc, DEQ(e0), q0);
        }

        // self-loop (table pre-scaled: add t[self], then scale whole row by dn)
        acc.x = (acc.x + bfu(svq, 0)) * dn;
        acc.y = (acc.y + bfu(svq, 1)) * dn;
        acc.z = (acc.z + bfu(svq, 2)) * dn;
        acc.w = (acc.w + bfu(svq, 3)) * dn;
        *reinterpret_cast<float4*>(&rowbuf[wv][g][l * 4]) = acc;
        __builtin_amdgcn_wave_barrier();

        // epilogue: 4 nodes; rowbuf via float4 broadcast, W from registers
        #pragma unroll 1
        for (int j = 0; j < 4; j++) {
            int onode = base + j;
            if (onode >= n) break;
            float o = 0.f;
            #pragma unroll
            for (int k4 = 0; k4 < 16; k4++) {
                float4 r = *reinterpret_cast<const float4*>(&rowbuf[wv][j][k4 * 4]);
                o = fmaf(r.x, wr[k4 * 4 + 0], o);
                o = fmaf(r.y, wr[k4 * 4 + 1], o);
                o = fmaf(r.z, wr[k4 * 4 + 2], o);
                o = fmaf(r.w, wr[k4 * 4 + 3], o);
            }
            o += bl;
            if (RELU) {
                o = fmaxf(o, 0.f);
                OutB[(size_t)onode * DIM + lane] = f2bf(o * dinv[onode]);
            } else {
                OutF[(size_t)onode * DIM + lane] = o;
            }
        }
        __builtin_amdgcn_wave_barrier();
    }
}

extern "C" void kernel_launch(void* const* d_in, const int* in_sizes, int n_in,
                              void* d_out, int out_size, void* d_ws, size_t ws_size,
                              hipStream_t stream) {
    const float* x  = (const float*)d_in[0];
    const int* ei   = (const int*)d_in[1];   // [2][NE] int32
    const float* ew = (const float*)d_in[2];
    const float* W1 = (const float*)d_in[3];
    const float* b1 = (const float*)d_in[4];
    const float* W2 = (const float*)d_in[5];
    const float* b2 = (const float*)d_in[6];
    const float* W3 = (const float*)d_in[7];
    const float* b3 = (const float*)d_in[8];
    float* out = (float*)d_out;

    const int* src = ei;
    const int* dst = ei + NE;

    auto align = [](size_t v) { return (v + 255) / 256 * 256; };
    char* ws = (char*)d_ws;
    // persistent:
    int*      row_ptr = (int*)ws;      ws += align(((size_t)NN + 1) * 4);
    float*    dinv    = (float*)ws;    ws += align((size_t)NN * 4);
    unsigned* edata   = (unsigned*)ws; ws += align((size_t)NE * 4);        // 6.4 MB
    ushort*   Hb0     = (ushort*)ws;   ws += align((size_t)NN * DIM * 2);  // 12.8 MB
    ushort*   A1b     = (ushort*)ws;   ws += align((size_t)NN * DIM * 2);  // 12.8 MB
    ushort*   A2b     = (ushort*)ws;   ws += align((size_t)NN * DIM * 2);  // 12.8 MB
    // build temporaries (no overlay needed):
    int*  gcounts = (int*)ws;  ws += align((size_t)NBINP * NCHUNKP * 4);   // 4 MB
    int*  bintot  = (int*)ws;  ws += align((size_t)NBINP * 4);
    int*  binbase = (int*)ws;  ws += align(((size_t)NBINP + 1) * 4);
    int2* binned  = (int2*)ws;                                             // 12.8 MB

    const int gL = 2048;

    // ---- deterministic CSR build: zero global atomics ----
    k_hist<<<NCHUNKP, 256, 0, stream>>>(dst, gcounts);
    k_colscan<<<NBINP, 256, 0, stream>>>(gcounts, bintot);
    k_binscan<<<1, 256, 0, stream>>>(bintot, binbase, row_ptr);
    k_scatbin<<<NCHUNKP, 256, 0, stream>>>(src, dst, ew, gcounts, binbase, binned);
    k_group<<<NBIN, 256, 0, stream>>>(binned, binbase, x, edata, row_ptr, dinv, Hb0);

    // ---- fused layers: pre-scaled bf16 tables, packed edges, fp32 math ----
    k_layer<1><<<gL, 256, 0, stream>>>(row_ptr, edata, Hb0, W1, b1, dinv, A1b, nullptr, NN);
    k_layer<1><<<gL, 256, 0, stream>>>(row_ptr, edata, A1b, W2, b2, dinv, A2b, nullptr, NN);
    k_layer<0><<<gL, 256, 0, stream>>>(row_ptr, edata, A2b, W3, b3, dinv, nullptr, out, NN);
}

// Round 17
// 215.169 us; speedup vs baseline: 10.2347x; 1.0466x over previous
//
#include <hip/hip_runtime.h>

#define NN 100000
#define NE 1600000
#define DIM 64
#define NPB 128            // nodes per bin
#define NBIN 782           // ceil(NN / NPB)
#define NBINP 1024         // padded for scans
#define ECHUNK 8192        // edges per chunk (long runs per (chunk,bin) segment)
#define NCHUNK ((NE + ECHUNK - 1) / ECHUNK)   // 196
#define NCHUNKP 256        // padded chunk count; k_hist MUST launch NCHUNKP blocks
                           // so tail chunks (196..255) write zero counts (r16 bug)

__device__ inline ushort f2bf(float f) {            // round-to-nearest-even
    unsigned u = __float_as_uint(f);
    unsigned r = u + 0x7FFFu + ((u >> 16) & 1u);
    return (ushort)(r >> 16);
}
__device__ inline float bfu(unsigned long long v, int k) {   // bf16 lane k of u64
    return __uint_as_float((unsigned)((v >> (k * 16)) & 0xFFFFu) << 16);
}

// Per-chunk histogram over bins (LDS atomics only). gcounts layout: [bin][chunk].
// Launched with NCHUNKP blocks: chunks >= NCHUNK write zeros (padding!).
__global__ __launch_bounds__(256) void k_hist(const int* __restrict__ dst,
                                              int* __restrict__ gcounts) {
    __shared__ int hist[NBINP];
    int tid = threadIdx.x, chunk = blockIdx.x;
    for (int j = tid; j < NBINP; j += 256) hist[j] = 0;
    __syncthreads();
    int base = chunk * ECHUNK;
    int lim = min(base + ECHUNK, NE);
    for (int i = base + tid; i < lim; i += 256)
        atomicAdd(&hist[dst[i] >> 7], 1);
    __syncthreads();
    for (int j = tid; j < NBINP; j += 256)
        gcounts[j * NCHUNKP + chunk] = hist[j];
}

// Per-bin exclusive scan over the (<=256) chunk axis, in place.
__global__ __launch_bounds__(256) void k_colscan(int* __restrict__ gcounts,
                                                 int* __restrict__ bintot) {
    __shared__ int sd[256];
    int t = threadIdx.x;
    int* p = gcounts + blockIdx.x * NCHUNKP;
    int v = p[t];
    sd[t] = v;
    __syncthreads();
    for (int off = 1; off < 256; off <<= 1) {
        int x = (t >= off) ? sd[t - off] : 0;
        __syncthreads();
        sd[t] += x;
        __syncthreads();
    }
    p[t] = sd[t] - v;                  // exclusive
    if (t == 255) bintot[blockIdx.x] = sd[255];
}

// Exclusive scan of 1024 bin totals -> binbase; also row_ptr[NN] = NE.
__global__ __launch_bounds__(256) void k_binscan(const int* __restrict__ bintot,
                                                 int* __restrict__ binbase,
                                                 int* __restrict__ row_ptr) {
    __shared__ int sd[256];
    int t = threadIdx.x;
    int v[4], s = 0;
    #pragma unroll
    for (int i = 0; i < 4; i++) { v[i] = bintot[t * 4 + i]; s += v[i]; }
    sd[t] = s;
    __syncthreads();
    for (int off = 1; off < 256; off <<= 1) {
        int x = (t >= off) ? sd[t - off] : 0;
        __syncthreads();
        sd[t] += x;
        __syncthreads();
    }
    int excl = sd[t] - s;
    #pragma unroll
    for (int i = 0; i < 4; i++) { binbase[t * 4 + i] = excl; excl += v[i]; }
    if (t == 255) { binbase[NBINP] = sd[255]; row_ptr[NN] = sd[255]; }
}

// Stable scatter of edges into their bin's contiguous range. No global atomics.
// meta = src (17b) | dst_local (7b) << 17
__global__ __launch_bounds__(256) void k_scatbin(const int* __restrict__ src,
                                                 const int* __restrict__ dst,
                                                 const float* __restrict__ w,
                                                 const int* __restrict__ gcounts,
                                                 const int* __restrict__ binbase,
                                                 int2* __restrict__ binned) {
    __shared__ int lcur[NBINP];
    int tid = threadIdx.x, chunk = blockIdx.x;
    for (int j = tid; j < NBINP; j += 256) lcur[j] = 0;
    __syncthreads();
    int base = chunk * ECHUNK;
    int lim = min(base + ECHUNK, NE);
    for (int i = base + tid; i < lim; i += 256) {
        int d = dst[i];
        int b = d >> 7;
        int r = atomicAdd(&lcur[b], 1);                       // LDS atomic
        int pos = binbase[b] + gcounts[b * NCHUNKP + chunk] + r;
        int meta = src[i] | ((d & 127) << 17);
        binned[pos] = make_int2(meta, __float_as_int(w[i]));
    }
}

// Per-bin: per-node grouping + row_ptr + dinv + PACKED edata (src<<15 | q15(w))
// + bf16 pre-scaled table conversion for this bin's 128 x-rows (k_cvt folded in).
__global__ __launch_bounds__(256) void k_group(const int2* __restrict__ binned,
                                               const int* __restrict__ binbase,
                                               const float* __restrict__ x,
                                               unsigned* __restrict__ edata,
                                               int* __restrict__ row_ptr,
                                               float* __restrict__ dinv,
                                               ushort* __restrict__ Hb0) {
    __shared__ int ndeg[NPB];
    __shared__ float nws[NPB];     // weight sums, then dinv values
    __shared__ int ncur[NPB];
    __shared__ int sd[NPB];
    int t = threadIdx.x, bin = blockIdx.x;
    int beg = binbase[bin], end = binbase[bin + 1];
    if (t < NPB) { ndeg[t] = 0; nws[t] = 0.f; }
    __syncthreads();
    for (int e = beg + t; e < end; e += 256) {
        int2 v = binned[e];
        int dl = ((unsigned)v.x) >> 17;
        atomicAdd(&ndeg[dl], 1);
        atomicAdd(&nws[dl], __int_as_float(v.y));
    }
    __syncthreads();
    int own = 0;
    if (t < NPB) { own = ndeg[t]; sd[t] = own; }
    __syncthreads();
    for (int off = 1; off < NPB; off <<= 1) {
        int xx = (t >= off && t < NPB) ? sd[t - off] : 0;
        __syncthreads();
        if (t < NPB) sd[t] += xx;
        __syncthreads();
    }
    if (t < NPB) {
        int excl = sd[t] - own;
        ncur[t] = excl;
        float dv = rsqrtf(1.0f + nws[t]);
        nws[t] = dv;                       // nws now holds dinv
        int node = bin * NPB + t;
        if (node < NN) {
            row_ptr[node] = beg + excl;
            dinv[node] = dv;
        }
    }
    __syncthreads();
    // scatter to packed per-node edata
    for (int e = beg + t; e < end; e += 256) {
        int2 v = binned[e];
        int dl = ((unsigned)v.x) >> 17;
        int r = atomicAdd(&ncur[dl], 1);
        unsigned q15 = __float2uint_rn(__int_as_float(v.y) * 32767.0f);
        edata[beg + r] = ((unsigned)(v.x & 0x1FFFF) << 15) | q15;
    }
    // bf16 pre-scaled table for this bin's rows: Hb0[node] = dinv[node]*x[node]
    int rowlim = min(NPB, NN - bin * NPB);
    for (int idx = t; idx < rowlim * 16; idx += 256) {    // 16 float4 per row
        int row = idx >> 4;
        int node = bin * NPB + row;
        float dn = nws[row];
        float4 v = reinterpret_cast<const float4*>(x)[(size_t)node * 16 + (idx & 15)];
        ushort4 o;
        o.x = f2bf(v.x * dn); o.y = f2bf(v.y * dn);
        o.z = f2bf(v.z * dn); o.w = f2bf(v.w * dn);
        reinterpret_cast<ushort4*>(Hb0)[(size_t)node * 16 + (idx & 15)] = o;
    }
}

#define FMA4U(acc, nm, q) \
    acc.x = fmaf(nm, bfu(q, 0), acc.x); acc.y = fmaf(nm, bfu(q, 1), acc.y); \
    acc.z = fmaf(nm, bfu(q, 2), acc.z); acc.w = fmaf(nm, bfu(q, 3), acc.w);

// Plain (cached) 8B bf16x4 row-slice gather — L1/L2 retention helps (r12 lesson).
#define LDROW(idx) (*reinterpret_cast<const unsigned long long*>( \
    Hb + ((size_t)(idx) << 6) + (l << 2)))
#define DEQ(v) ((float)((v) & 0x7FFFu) * (1.0f / 32767.0f))

// Fused layer. ONE NODE PER 16-LANE GROUP (4 consecutive nodes per wave).
// Table Hb is PRE-SCALED: t[s] = dinv[s]*A[s]. edata = (src<<15)|q15(w).
// Epilogue: W column in 64 VGPRs; rowbuf via uniform-address float4 broadcasts.
template <int RELU>
__global__ __launch_bounds__(256, 4) void k_layer(const int* __restrict__ row_ptr,
                                                  const unsigned* __restrict__ edata,
                                                  const ushort* __restrict__ Hb,
                                                  const float* __restrict__ W,
                                                  const float* __restrict__ bias,
                                                  const float* __restrict__ dinv,
                                                  ushort* __restrict__ OutB,
                                                  float* __restrict__ OutF, int n) {
    __shared__ float rowbuf[4][4][68];   // [wave][group/node][ch pad 68] 4.3 KB
    int tid = threadIdx.x;
    int lane = tid & 63, wv = tid >> 6;
    int g = lane >> 4, l = lane & 15;

    // my output column of W in registers (64 coalesced loads, static indexing)
    float wr[64];
    #pragma unroll
    for (int k = 0; k < 64; k++) wr[k] = W[k * 64 + lane];
    float bl = bias[lane];

    int wave_id = blockIdx.x * 4 + wv;
    int nwaves = gridDim.x * 4;

    for (int base = wave_id * 4; base < n; base += nwaves * 4) {
        int node = base + g;
        bool valid = node < n;
        int beg = 0, end = 0;
        float dn = 0.f;
        if (valid) { beg = row_ptr[node]; end = row_ptr[node + 1]; dn = dinv[node]; }
        // self-row (pre-scaled) issued early
        unsigned long long svq = LDROW(valid ? node : 0);

        float4 acc = make_float4(0.f, 0.f, 0.f, 0.f);
        int e = beg;
        for (; e + 7 < end; e += 8) {          // 8 gathers in flight per group
            unsigned ev[8];
            unsigned long long q[8];
            #pragma unroll
            for (int u = 0; u < 8; u++) ev[u] = edata[e + u];
            #pragma unroll
            for (int u = 0; u < 8; u++) q[u] = LDROW(ev[u] >> 15);
            #pragma unroll
            for (int u = 0; u < 8; u++) {
                float nm = DEQ(ev[u]);
                FMA4U(acc, nm, q[u]);
            }
        }
        if (e + 3 < end) {
            unsigned ev[4];
            unsigned long long q[4];
            #pragma unroll
            for (int u = 0; u < 4; u++) ev[u] = edata[e + u];
            #pragma unroll
            for (int u = 0; u < 4; u++) q[u] = LDROW(ev[u] >> 15);
            #pragma unroll
            for (int u = 0; u < 4; u++) {
                float nm = DEQ(ev[u]);
                FMA4U(acc, nm, q[u]);
            }
            e += 4;
        }
        if (e + 1 < end) {
            unsigned e0 = edata[e], e1 = edata[e + 1];
            unsigned long long q0 = LDROW(e0 >> 15), q1 = LDROW(e1 >> 15);
            FMA4U(acc, DEQ(e0), q0); FMA4U(acc, DEQ(e1), q1);
            e += 2;
        }
        if (e < end) {
            unsigned e0 = edata[e];
            unsigned long long q0 = LDROW(e0 >> 15);
            FMA4U(acc, DEQ(e0), q0);
        }

        // self-loop (table pre-scaled: add t[self], then scale whole row by dn)
        acc.x = (acc.x + bfu(svq, 0)) * dn;
        acc.y = (acc.y + bfu(svq, 1)) * dn;
        acc.z = (acc.z + bfu(svq, 2)) * dn;
        acc.w = (acc.w + bfu(svq, 3)) * dn;
        *reinterpret_cast<float4*>(&rowbuf[wv][g][l * 4]) = acc;
        __builtin_amdgcn_wave_barrier();

        // epilogue: 4 nodes; rowbuf via float4 broadcast, W from registers
        #pragma unroll 1
        for (int j = 0; j < 4; j++) {
            int onode = base + j;
            if (onode >= n) break;
            float o = 0.f;
            #pragma unroll
            for (int k4 = 0; k4 < 16; k4++) {
                float4 r = *reinterpret_cast<const float4*>(&rowbuf[wv][j][k4 * 4]);
                o = fmaf(r.x, wr[k4 * 4 + 0], o);
                o = fmaf(r.y, wr[k4 * 4 + 1], o);
                o = fmaf(r.z, wr[k4 * 4 + 2], o);
                o = fmaf(r.w, wr[k4 * 4 + 3], o);
            }
            o += bl;
            if (RELU) {
                o = fmaxf(o, 0.f);
                OutB[(size_t)onode * DIM + lane] = f2bf(o * dinv[onode]);
            } else {
                OutF[(size_t)onode * DIM + lane] = o;
            }
        }
        __builtin_amdgcn_wave_barrier();
    }
}

extern "C" void kernel_launch(void* const* d_in, const int* in_sizes, int n_in,
                              void* d_out, int out_size, void* d_ws, size_t ws_size,
                              hipStream_t stream) {
    const float* x  = (const float*)d_in[0];
    const int* ei   = (const int*)d_in[1];   // [2][NE] int32
    const float* ew = (const float*)d_in[2];
    const float* W1 = (const float*)d_in[3];
    const float* b1 = (const float*)d_in[4];
    const float* W2 = (const float*)d_in[5];
    const float* b2 = (const float*)d_in[6];
    const float* W3 = (const float*)d_in[7];
    const float* b3 = (const float*)d_in[8];
    float* out = (float*)d_out;

    const int* src = ei;
    const int* dst = ei + NE;

    auto align = [](size_t v) { return (v + 255) / 256 * 256; };
    char* ws = (char*)d_ws;
    // persistent:
    int*      row_ptr = (int*)ws;      ws += align(((size_t)NN + 1) * 4);
    float*    dinv    = (float*)ws;    ws += align((size_t)NN * 4);
    unsigned* edata   = (unsigned*)ws; ws += align((size_t)NE * 4);        // 6.4 MB
    ushort*   Hb0     = (ushort*)ws;   ws += align((size_t)NN * DIM * 2);  // 12.8 MB
    ushort*   A1b     = (ushort*)ws;   ws += align((size_t)NN * DIM * 2);  // 12.8 MB
    ushort*   A2b     = (ushort*)ws;   ws += align((size_t)NN * DIM * 2);  // 12.8 MB
    // build temporaries:
    int*  gcounts = (int*)ws;  ws += align((size_t)NBINP * NCHUNKP * 4);   // 1 MB
    int*  bintot  = (int*)ws;  ws += align((size_t)NBINP * 4);
    int*  binbase = (int*)ws;  ws += align(((size_t)NBINP + 1) * 4);
    int2* binned  = (int2*)ws;                                             // 12.8 MB

    const int gL = 2048;

    // ---- deterministic CSR build: zero global atomics ----
    // NCHUNKP blocks (not NCHUNK): tail chunks must write zero counts.
    k_hist<<<NCHUNKP, 256, 0, stream>>>(dst, gcounts);
    k_colscan<<<NBINP, 256, 0, stream>>>(gcounts, bintot);
    k_binscan<<<1, 256, 0, stream>>>(bintot, binbase, row_ptr);
    k_scatbin<<<NCHUNK, 256, 0, stream>>>(src, dst, ew, gcounts, binbase, binned);
    k_group<<<NBIN, 256, 0, stream>>>(binned, binbase, x, edata, row_ptr, dinv, Hb0);

    // ---- fused layers: pre-scaled bf16 tables, packed edges, fp32 math ----
    k_layer<1><<<gL, 256, 0, stream>>>(row_ptr, edata, Hb0, W1, b1, dinv, A1b, nullptr, NN);
    k_layer<1><<<gL, 256, 0, stream>>>(row_ptr, edata, A1b, W2, b2, dinv, A2b, nullptr, NN);
    k_layer<0><<<gL, 256, 0, stream>>>(row_ptr, edata, A2b, W3, b3, dinv, nullptr, out, NN);
}